// Round 8
// baseline (205.076 us; speedup 1.0000x reference)
//
#include <hip/hip_runtime.h>
#include <math.h>

#define IS3 0.57735026918962576f   // 1/sqrt(3)
#define IS6 0.40824829046386302f   // 1/sqrt(6)

#define SHIFT 11                   // 2048 nodes per bucket
#define BSZ   2048
#define CAP   36864u               // slots per bucket (mean 32653, +23 sigma)
#define SEG   6                    // K2 workgroups per bucket
#define MQ    4096.0f              // message quantization scale (i16)
#define IMQ   (1.0f/4096.0f)

__device__ __forceinline__ float fastrcp(float x) { return __builtin_amdgcn_rcpf(x); }

// T(x) = tanh(w2 * tanh(w1*x)).
// Inner tanh: exp-based (1 v_exp + 1 v_rcp). Outer tanh: odd poly
// z - z^3/3 + 2z^5/15 (|z| <= |w2| ~ 0.3 -> err <= ~4e-4, vs 0.1 budget).
// tw1 = 2*w1 precomputed.
__device__ __forceinline__ float Tnl(float x, float tw1, float w2) {
    float e = __expf(tw1 * x);
    float u = 1.0f - 2.0f * fastrcp(e + 1.0f);   // tanh(w1*x)
    float z = w2 * u;
    float z2 = z * z;
    float p = __builtin_fmaf(z2, 0.133333333f, -0.333333333f);
    return __builtin_fmaf(z * z2, p, z);
}

__device__ __forceinline__ int q16(float x) {
    int v = (int)rintf(x * MQ);
    v = v >  32767 ?  32767 : v;
    v = v < -32768 ? -32768 : v;
    return v;
}

// ---- K1: fused message compute + bucket routing.
__global__ __launch_bounds__(1024) void route_kernel(
    const int* __restrict__ ei, const float* __restrict__ f,
    const float* __restrict__ d, const float* __restrict__ a,
    const float* __restrict__ w1p, const float* __restrict__ w2p,
    unsigned* __restrict__ tails,        // [nbuk*64] padded, pre-zeroed
    unsigned* __restrict__ qmeta,        // [nbuk*CAP]
    uint2* __restrict__ qmsg,            // [nbuk*CAP]
    int E, int nbuk)
{
    __shared__ unsigned hcnt[64];
    __shared__ unsigned hoff[64];
    int tid = threadIdx.x;
    if (tid < 64) hcnt[tid] = 0;
    __syncthreads();

    int e = blockIdx.x * 1024 + tid;
    bool valid = (e < E);
    int t = 0;
    unsigned b = 0, lrank = 0;
    if (valid) {
        t = ei[E + e];
        b = ((unsigned)t) >> SHIFT;
        lrank = atomicAdd(&hcnt[b], 1u);        // LDS int atomic (native)
    }
    __syncthreads();

    unsigned basek = 0;
    if (tid < nbuk && hcnt[tid] != 0u)
        basek = atomicAdd(&tails[tid * 64], hcnt[tid]);

    unsigned dq = 0;
    uint2 pk = make_uint2(0u, 0u);
    if (valid) {
        int s = ei[e];
        float tw10 = 2.0f * w1p[0], tw11 = 2.0f * w1p[1];
        float w20 = w2p[0], w21 = w2p[1];

        const float4* f4 = (const float4*)f;
        float4 sA = f4[2*s], sB = f4[2*s+1];
        float4 tA = f4[2*t], tB = f4[2*t+1];
        float de = d[e];
        float4 av = ((const float4*)a)[e];
        float a0 = av.x, ax = av.y, ay = av.z, az = av.w;

        float sc[5] = { sA.x, sA.y, tA.x, tA.y, de };
        float vx[4] = { sA.z, sB.y, tA.z, tB.y };
        float vy[4] = { sA.w, sB.z, tA.w, tB.z };
        float vz[4] = { sB.x, sB.w, tB.x, tB.w };

        float mS = 0.f, mX = 0.f, mY = 0.f, mZ = 0.f;
        #pragma unroll
        for (int i = 0; i < 5; ++i) {
            mS += Tnl(sc[i] * a0, tw10, w20);
            mX += Tnl(sc[i] * ax * IS3, tw11, w21);
            mY += Tnl(sc[i] * ay * IS3, tw11, w21);
            mZ += Tnl(sc[i] * az * IS3, tw11, w21);
        }
        #pragma unroll
        for (int i = 0; i < 4; ++i) {
            float dva = vx[i]*ax + vy[i]*ay + vz[i]*az;
            mS += Tnl(dva * IS3, tw11, w21);
            mX += Tnl(vx[i] * a0 * IS3, tw10, w20);
            mY += Tnl(vy[i] * a0 * IS3, tw10, w20);
            mZ += Tnl(vz[i] * a0 * IS3, tw10, w20);
            float cx = vy[i]*az - vz[i]*ay;
            float cy = vz[i]*ax - vx[i]*az;
            float cz = vx[i]*ay - vy[i]*ax;
            mX += Tnl(cx * IS6, tw11, w21);
            mY += Tnl(cy * IS6, tw11, w21);
            mZ += Tnl(cz * IS6, tw11, w21);
        }

        unsigned dqi = (unsigned)(de * 2047.0f + 0.5f);
        dq = dqi > 2047u ? 2047u : dqi;
        int qS = q16(mS), qX = q16(mX), qY = q16(mY), qZ = q16(mZ);
        pk.x = ((unsigned)(unsigned short)qS) | (((unsigned)(unsigned short)qX) << 16);
        pk.y = ((unsigned)(unsigned short)qY) | (((unsigned)(unsigned short)qZ) << 16);
    }

    if (tid < nbuk) hoff[tid] = basek;   // s_waitcnt lands here, post-compute
    __syncthreads();

    if (valid) {
        unsigned pos = hoff[b] + lrank;
        if (pos < CAP) {                 // safety clamp; never hit
            size_t idx = (size_t)b * CAP + pos;
            qmeta[idx] = (((unsigned)(t & (BSZ - 1))) << 11) | dq;
            qmsg[idx]  = pk;
        }
    }
}

// ---- K2: one workgroup per (bucket, segment). 3 native LDS atomics per
// record: two ds_add_u64 (bias-packed {S,X} and {Y,Z}: low field biased
// +2^16 so it stays positive and never carries into the high field) + one
// u32 for (cnt<<20)|dq. Flush = 5 coalesced SoA planes of raw u32.
__global__ __launch_bounds__(1024) void bucket_kernel(
    const unsigned* __restrict__ tails, const unsigned* __restrict__ qmeta,
    const uint2* __restrict__ qmsg, unsigned* __restrict__ partial, int nbuk)
{
    __shared__ unsigned long long accSX[BSZ];   // 16KB
    __shared__ unsigned long long accYZ[BSZ];   // 16KB
    __shared__ unsigned accM[BSZ];              // 8KB
    int wg = blockIdx.x;
    int b = wg / SEG, sgi = wg % SEG;
    for (int i = threadIdx.x; i < BSZ; i += 1024) {
        accSX[i] = 0ull; accYZ[i] = 0ull; accM[i] = 0u;
    }
    __syncthreads();

    unsigned tail = tails[b * 64];
    if (tail > CAP) tail = CAP;
    unsigned lo = (unsigned)(((unsigned long long)tail * sgi) / SEG);
    unsigned hi = (unsigned)(((unsigned long long)tail * (sgi + 1)) / SEG);
    size_t base = (size_t)b * CAP;

    for (unsigned q = lo + threadIdx.x; q < hi; q += 1024) {
        unsigned meta = qmeta[base + q];
        uint2 m = qmsg[base + q];
        int local = (int)(meta >> 11);
        int qS = (int)(short)(m.x & 0xFFFFu);
        int qX = (int)(short)(m.x >> 16);
        int qY = (int)(short)(m.y & 0xFFFFu);
        int qZ = (int)(short)(m.y >> 16);
        unsigned long long vSX =
            (((unsigned long long)(unsigned)qX) << 32) | (unsigned)(qS + 65536);
        unsigned long long vYZ =
            (((unsigned long long)(unsigned)qZ) << 32) | (unsigned)(qY + 65536);
        atomicAdd(&accSX[local], vSX);
        atomicAdd(&accYZ[local], vYZ);
        atomicAdd(&accM[local], (1u << 20) | (meta & 2047u));
    }
    __syncthreads();

    unsigned* dst = partial + (size_t)wg * (BSZ * 5);
    for (int i = threadIdx.x; i < BSZ; i += 1024) {
        unsigned long long sx = accSX[i], yz = accYZ[i];
        dst[0*BSZ + i] = (unsigned)sx;
        dst[1*BSZ + i] = (unsigned)(sx >> 32);
        dst[2*BSZ + i] = (unsigned)yz;
        dst[3*BSZ + i] = (unsigned)(yz >> 32);
        dst[4*BSZ + i] = accM[i];
    }
}

// ---- K3: decode+sum SEG partials (exact int) + invariants + MLP + out.
// Weights read directly from global via wave-uniform indices -> s_load
// through the scalar/constant cache (native broadcast, no LDS round-trip).
__global__ __launch_bounds__(256) void mlp_kernel(
    const float* __restrict__ f, const unsigned* __restrict__ partial,
    const float* __restrict__ W0, const float* __restrict__ b0,
    const float* __restrict__ W1, const float* __restrict__ b1,
    const float* __restrict__ W2, const float* __restrict__ b2,
    float* __restrict__ out, int N)
{
    int n = blockIdx.x * 256 + threadIdx.x;
    if (n >= N) return;

    int b = n >> SHIFT;
    int local = n & (BSZ - 1);
    int S = 0, X = 0, Y = 0, Z = 0, cnt = 0, dqs = 0;
    #pragma unroll
    for (int s2 = 0; s2 < SEG; ++s2) {
        const unsigned* p = partial + ((size_t)(b * SEG + s2)) * (BSZ * 5);
        unsigned m4 = p[4*BSZ + local];
        int c = (int)(m4 >> 20);
        S += (int)p[0*BSZ + local] - (c << 16);
        X += (int)p[1*BSZ + local];
        Y += (int)p[2*BSZ + local] - (c << 16);
        Z += (int)p[3*BSZ + local];
        dqs += (int)(m4 & 0xFFFFFu);
        cnt += c;
    }
    float aS = (float)S * IMQ, ax = (float)X * IMQ;
    float ay = (float)Y * IMQ, az = (float)Z * IMQ;
    float cf = (float)cnt;
    float dsum = (float)dqs * (1.0f / 2047.0f);

    float4 fA = ((const float4*)f)[2*n];
    float4 fB = ((const float4*)f)[2*n+1];

    float psi[9];
    psi[0] = fA.x; psi[1] = fA.y;
    psi[2] = sqrtf(fA.z*fA.z + fA.w*fA.w + fB.x*fB.x);
    psi[3] = sqrtf(fB.y*fB.y + fB.z*fB.z + fB.w*fB.w);
    psi[4] = aS; psi[5] = aS;
    float nv = sqrtf(ax*ax + ay*ay + az*az);
    psi[6] = nv; psi[7] = nv;
    psi[8] = dsum * fastrcp(cf + 1e-8f);

    // layer1+layer2 interleaved: x0_i folded into x1 immediately (no spills)
    float x1[32];
    #pragma unroll
    for (int j = 0; j < 32; ++j) x1[j] = b1[j];
    #pragma unroll
    for (int i = 0; i < 64; ++i) {
        float acc = b0[i];
        #pragma unroll
        for (int k = 0; k < 9; ++k) acc += psi[k] * W0[k*64 + i];
        acc = fmaxf(acc, 0.f);
        #pragma unroll
        for (int j = 0; j < 32; ++j) x1[j] += acc * W1[i*32 + j];
    }
    #pragma unroll
    for (int j = 0; j < 32; ++j) x1[j] = fmaxf(x1[j], 0.f);

    float g[4];
    #pragma unroll
    for (int j = 0; j < 4; ++j) {
        float acc = b2[j];
        #pragma unroll
        for (int i = 0; i < 32; ++i) acc += x1[i] * W2[i*4 + j];
        g[j] = fastrcp(1.0f + __expf(-acc));   // sigmoid
    }

    float* o = out + (size_t)8*n;
    o[0] = fA.x + g[0]*aS;
    o[1] = fA.y + g[1]*aS;
    o[2] = fA.z + g[2]*ax;
    o[3] = fA.w + g[2]*ay;
    o[4] = fB.x + g[2]*az;
    o[5] = fB.y + g[3]*ax;
    o[6] = fB.z + g[3]*ay;
    o[7] = fB.w + g[3]*az;
}

extern "C" void kernel_launch(void* const* d_in, const int* in_sizes, int n_in,
                              void* d_out, int out_size, void* d_ws, size_t ws_size,
                              hipStream_t stream) {
    const int*   ei = (const int*)d_in[0];
    const float* f  = (const float*)d_in[1];
    const float* d  = (const float*)d_in[2];
    const float* a  = (const float*)d_in[3];
    const float* w1 = (const float*)d_in[4];
    const float* w2 = (const float*)d_in[5];
    const float* W0 = (const float*)d_in[6];
    const float* b0 = (const float*)d_in[7];
    const float* W1 = (const float*)d_in[8];
    const float* b1 = (const float*)d_in[9];
    const float* W2 = (const float*)d_in[10];
    const float* b2 = (const float*)d_in[11];
    int E = in_sizes[0] / 2;
    int N = in_sizes[1] / 8;
    int nbuk = (N + BSZ - 1) >> SHIFT;          // 49 for N=100000

    // workspace layout (bytes), total ~33.7 MB:
    //   qmsg    : nbuk*CAP*8       @ 0
    //   qmeta   : nbuk*CAP*4       @ qmsg_end
    //   partial : nbuk*SEG*BSZ*5*4 @ qmeta_end
    //   tails   : nbuk*64*4        @ partial_end (zeroed)
    char* w = (char*)d_ws;
    size_t qn = (size_t)nbuk * CAP;
    uint2*    qmsg    = (uint2*)w;
    unsigned* qmeta   = (unsigned*)(w + qn * 8);
    unsigned* partial = (unsigned*)(w + qn * 12);
    unsigned* tails   = (unsigned*)(w + qn * 12
                        + (size_t)nbuk * SEG * BSZ * 5 * 4);

    hipMemsetAsync(tails, 0, (size_t)nbuk * 64 * sizeof(unsigned), stream);

    int EB = (E + 1023) / 1024;     // 1563
    route_kernel <<<dim3(EB), dim3(1024), 0, stream>>>(
        ei, f, d, a, w1, w2, tails, qmeta, qmsg, E, nbuk);
    bucket_kernel<<<dim3(nbuk * SEG), dim3(1024), 0, stream>>>(
        tails, qmeta, qmsg, partial, nbuk);
    mlp_kernel   <<<dim3((N + 255) / 256), dim3(256), 0, stream>>>(
        f, partial, W0, b0, W1, b1, W2, b2, (float*)d_out, N);
}

// Round 9
// 175.035 us; speedup vs baseline: 1.1716x; 1.1716x over previous
//
#include <hip/hip_runtime.h>
#include <math.h>

#define IS3 0.57735026918962576f   // 1/sqrt(3)
#define IS6 0.40824829046386302f   // 1/sqrt(6)

#define SHIFT 11                   // 2048 nodes per bucket
#define BSZ   2048
#define CAP   36864u               // slots per bucket (mean 32653, +23 sigma)
#define SEG   6                    // K2 workgroups per bucket
#define MQ    4096.0f              // message quantization scale (i16)
#define IMQ   (1.0f/4096.0f)

__device__ __forceinline__ float fastrcp(float x) { return __builtin_amdgcn_rcpf(x); }

// T(x) = tanh(w2 * tanh(w1*x)).
// Inner tanh: exp-based (1 v_exp + 1 v_rcp). Outer tanh: odd poly
// z - z^3/3 + 2z^5/15 (|z| <= |w2| ~ 0.3 -> err <= ~4e-4, vs 0.1 budget).
__device__ __forceinline__ float Tnl(float x, float tw1, float w2) {
    float e = __expf(tw1 * x);
    float u = 1.0f - 2.0f * fastrcp(e + 1.0f);   // tanh(w1*x)
    float z = w2 * u;
    float z2 = z * z;
    float p = __builtin_fmaf(z2, 0.133333333f, -0.333333333f);
    return __builtin_fmaf(z * z2, p, z);
}

__device__ __forceinline__ int q16(float x) {
    int v = (int)rintf(x * MQ);
    v = v >  32767 ?  32767 : v;
    v = v < -32768 ? -32768 : v;
    return v;
}

// ---- K1: fused message compute + bucket routing.
__global__ __launch_bounds__(1024) void route_kernel(
    const int* __restrict__ ei, const float* __restrict__ f,
    const float* __restrict__ d, const float* __restrict__ a,
    const float* __restrict__ w1p, const float* __restrict__ w2p,
    unsigned* __restrict__ tails,        // [nbuk*64] padded, pre-zeroed
    unsigned* __restrict__ qmeta,        // [nbuk*CAP]
    uint2* __restrict__ qmsg,            // [nbuk*CAP]
    int E, int nbuk)
{
    __shared__ unsigned hcnt[64];
    __shared__ unsigned hoff[64];
    int tid = threadIdx.x;
    if (tid < 64) hcnt[tid] = 0;
    __syncthreads();

    int e = blockIdx.x * 1024 + tid;
    bool valid = (e < E);
    int t = 0;
    unsigned b = 0, lrank = 0;
    if (valid) {
        t = ei[E + e];
        b = ((unsigned)t) >> SHIFT;
        lrank = atomicAdd(&hcnt[b], 1u);        // LDS int atomic (native)
    }
    __syncthreads();

    unsigned basek = 0;
    if (tid < nbuk && hcnt[tid] != 0u)
        basek = atomicAdd(&tails[tid * 64], hcnt[tid]);

    unsigned dq = 0;
    uint2 pk = make_uint2(0u, 0u);
    if (valid) {
        int s = ei[e];
        float tw10 = 2.0f * w1p[0], tw11 = 2.0f * w1p[1];
        float w20 = w2p[0], w21 = w2p[1];

        const float4* f4 = (const float4*)f;
        float4 sA = f4[2*s], sB = f4[2*s+1];
        float4 tA = f4[2*t], tB = f4[2*t+1];
        float de = d[e];
        float4 av = ((const float4*)a)[e];
        float a0 = av.x, ax = av.y, ay = av.z, az = av.w;

        float sc[5] = { sA.x, sA.y, tA.x, tA.y, de };
        float vx[4] = { sA.z, sB.y, tA.z, tB.y };
        float vy[4] = { sA.w, sB.z, tA.w, tB.z };
        float vz[4] = { sB.x, sB.w, tB.x, tB.w };

        float mS = 0.f, mX = 0.f, mY = 0.f, mZ = 0.f;
        #pragma unroll
        for (int i = 0; i < 5; ++i) {
            mS += Tnl(sc[i] * a0, tw10, w20);
            mX += Tnl(sc[i] * ax * IS3, tw11, w21);
            mY += Tnl(sc[i] * ay * IS3, tw11, w21);
            mZ += Tnl(sc[i] * az * IS3, tw11, w21);
        }
        #pragma unroll
        for (int i = 0; i < 4; ++i) {
            float dva = vx[i]*ax + vy[i]*ay + vz[i]*az;
            mS += Tnl(dva * IS3, tw11, w21);
            mX += Tnl(vx[i] * a0 * IS3, tw10, w20);
            mY += Tnl(vy[i] * a0 * IS3, tw10, w20);
            mZ += Tnl(vz[i] * a0 * IS3, tw10, w20);
            float cx = vy[i]*az - vz[i]*ay;
            float cy = vz[i]*ax - vx[i]*az;
            float cz = vx[i]*ay - vy[i]*ax;
            mX += Tnl(cx * IS6, tw11, w21);
            mY += Tnl(cy * IS6, tw11, w21);
            mZ += Tnl(cz * IS6, tw11, w21);
        }

        unsigned dqi = (unsigned)(de * 2047.0f + 0.5f);
        dq = dqi > 2047u ? 2047u : dqi;
        int qS = q16(mS), qX = q16(mX), qY = q16(mY), qZ = q16(mZ);
        pk.x = ((unsigned)(unsigned short)qS) | (((unsigned)(unsigned short)qX) << 16);
        pk.y = ((unsigned)(unsigned short)qY) | (((unsigned)(unsigned short)qZ) << 16);
    }

    if (tid < nbuk) hoff[tid] = basek;   // s_waitcnt lands here, post-compute
    __syncthreads();

    if (valid) {
        unsigned pos = hoff[b] + lrank;
        if (pos < CAP) {                 // safety clamp; never hit
            size_t idx = (size_t)b * CAP + pos;
            qmeta[idx] = (((unsigned)(t & (BSZ - 1))) << 11) | dq;
            qmsg[idx]  = pk;
        }
    }
}

// ---- K2: one workgroup per (bucket, segment). 3 native LDS atomics per
// record: two ds_add_u64 (bias-packed) + one u32. Flush = 5 SoA planes.
__global__ __launch_bounds__(1024) void bucket_kernel(
    const unsigned* __restrict__ tails, const unsigned* __restrict__ qmeta,
    const uint2* __restrict__ qmsg, unsigned* __restrict__ partial, int nbuk)
{
    __shared__ unsigned long long accSX[BSZ];   // 16KB
    __shared__ unsigned long long accYZ[BSZ];   // 16KB
    __shared__ unsigned accM[BSZ];              // 8KB
    int wg = blockIdx.x;
    int b = wg / SEG, sgi = wg % SEG;
    for (int i = threadIdx.x; i < BSZ; i += 1024) {
        accSX[i] = 0ull; accYZ[i] = 0ull; accM[i] = 0u;
    }
    __syncthreads();

    unsigned tail = tails[b * 64];
    if (tail > CAP) tail = CAP;
    unsigned lo = (unsigned)(((unsigned long long)tail * sgi) / SEG);
    unsigned hi = (unsigned)(((unsigned long long)tail * (sgi + 1)) / SEG);
    size_t base = (size_t)b * CAP;

    for (unsigned q = lo + threadIdx.x; q < hi; q += 1024) {
        unsigned meta = qmeta[base + q];
        uint2 m = qmsg[base + q];
        int local = (int)(meta >> 11);
        int qS = (int)(short)(m.x & 0xFFFFu);
        int qX = (int)(short)(m.x >> 16);
        int qY = (int)(short)(m.y & 0xFFFFu);
        int qZ = (int)(short)(m.y >> 16);
        unsigned long long vSX =
            (((unsigned long long)(unsigned)qX) << 32) | (unsigned)(qS + 65536);
        unsigned long long vYZ =
            (((unsigned long long)(unsigned)qZ) << 32) | (unsigned)(qY + 65536);
        atomicAdd(&accSX[local], vSX);
        atomicAdd(&accYZ[local], vYZ);
        atomicAdd(&accM[local], (1u << 20) | (meta & 2047u));
    }
    __syncthreads();

    unsigned* dst = partial + (size_t)wg * (BSZ * 5);
    for (int i = threadIdx.x; i < BSZ; i += 1024) {
        unsigned long long sx = accSX[i], yz = accYZ[i];
        dst[0*BSZ + i] = (unsigned)sx;
        dst[1*BSZ + i] = (unsigned)(sx >> 32);
        dst[2*BSZ + i] = (unsigned)yz;
        dst[3*BSZ + i] = (unsigned)(yz >> 32);
        dst[4*BSZ + i] = accM[i];
    }
}

// ---- K3: decode+sum SEG partials (exact int) + invariants + MLP + out.
// Weights staged in LDS (R7-proven; R8's global/s_load variant was 70us:
// 2852 unrolled scalar loads serialize on lgkmcnt with SGPR 112).
__global__ __launch_bounds__(256) void mlp_kernel(
    const float* __restrict__ f, const unsigned* __restrict__ partial,
    const float* __restrict__ W0, const float* __restrict__ b0,
    const float* __restrict__ W1, const float* __restrict__ b1,
    const float* __restrict__ W2, const float* __restrict__ b2,
    float* __restrict__ out, int N)
{
    __shared__ float sW0[9*64];
    __shared__ float sb0[64];
    __shared__ float sW1[64*32];
    __shared__ float sb1[32];
    __shared__ float sW2[32*4];
    __shared__ float sb2[4];
    for (int i = threadIdx.x; i < 9*64;  i += 256) sW0[i] = W0[i];
    for (int i = threadIdx.x; i < 64;    i += 256) sb0[i] = b0[i];
    for (int i = threadIdx.x; i < 64*32; i += 256) sW1[i] = W1[i];
    for (int i = threadIdx.x; i < 32;    i += 256) sb1[i] = b1[i];
    for (int i = threadIdx.x; i < 32*4;  i += 256) sW2[i] = W2[i];
    for (int i = threadIdx.x; i < 4;     i += 256) sb2[i] = b2[i];
    __syncthreads();

    int n = blockIdx.x * 256 + threadIdx.x;
    if (n >= N) return;

    int b = n >> SHIFT;
    int local = n & (BSZ - 1);
    int S = 0, X = 0, Y = 0, Z = 0, cnt = 0, dqs = 0;
    #pragma unroll
    for (int s2 = 0; s2 < SEG; ++s2) {
        const unsigned* p = partial + ((size_t)(b * SEG + s2)) * (BSZ * 5);
        unsigned m4 = p[4*BSZ + local];
        int c = (int)(m4 >> 20);
        S += (int)p[0*BSZ + local] - (c << 16);
        X += (int)p[1*BSZ + local];
        Y += (int)p[2*BSZ + local] - (c << 16);
        Z += (int)p[3*BSZ + local];
        dqs += (int)(m4 & 0xFFFFFu);
        cnt += c;
    }
    float aS = (float)S * IMQ, ax = (float)X * IMQ;
    float ay = (float)Y * IMQ, az = (float)Z * IMQ;
    float cf = (float)cnt;
    float dsum = (float)dqs * (1.0f / 2047.0f);

    float4 fA = ((const float4*)f)[2*n];
    float4 fB = ((const float4*)f)[2*n+1];

    float psi[9];
    psi[0] = fA.x; psi[1] = fA.y;
    psi[2] = sqrtf(fA.z*fA.z + fA.w*fA.w + fB.x*fB.x);
    psi[3] = sqrtf(fB.y*fB.y + fB.z*fB.z + fB.w*fB.w);
    psi[4] = aS; psi[5] = aS;
    float nv = sqrtf(ax*ax + ay*ay + az*az);
    psi[6] = nv; psi[7] = nv;
    psi[8] = dsum * fastrcp(cf + 1e-8f);

    // layer1+layer2 interleaved: x0_i folded into x1 immediately (no spills)
    float x1[32];
    #pragma unroll
    for (int j = 0; j < 32; ++j) x1[j] = sb1[j];
    #pragma unroll
    for (int i = 0; i < 64; ++i) {
        float acc = sb0[i];
        #pragma unroll
        for (int k = 0; k < 9; ++k) acc += psi[k] * sW0[k*64 + i];
        acc = fmaxf(acc, 0.f);
        #pragma unroll
        for (int j = 0; j < 32; ++j) x1[j] += acc * sW1[i*32 + j];
    }
    #pragma unroll
    for (int j = 0; j < 32; ++j) x1[j] = fmaxf(x1[j], 0.f);

    float g[4];
    #pragma unroll
    for (int j = 0; j < 4; ++j) {
        float acc = sb2[j];
        #pragma unroll
        for (int i = 0; i < 32; ++i) acc += x1[i] * sW2[i*4 + j];
        g[j] = fastrcp(1.0f + __expf(-acc));   // sigmoid
    }

    float* o = out + (size_t)8*n;
    o[0] = fA.x + g[0]*aS;
    o[1] = fA.y + g[1]*aS;
    o[2] = fA.z + g[2]*ax;
    o[3] = fA.w + g[2]*ay;
    o[4] = fB.x + g[2]*az;
    o[5] = fB.y + g[3]*ax;
    o[6] = fB.z + g[3]*ay;
    o[7] = fB.w + g[3]*az;
}

extern "C" void kernel_launch(void* const* d_in, const int* in_sizes, int n_in,
                              void* d_out, int out_size, void* d_ws, size_t ws_size,
                              hipStream_t stream) {
    const int*   ei = (const int*)d_in[0];
    const float* f  = (const float*)d_in[1];
    const float* d  = (const float*)d_in[2];
    const float* a  = (const float*)d_in[3];
    const float* w1 = (const float*)d_in[4];
    const float* w2 = (const float*)d_in[5];
    const float* W0 = (const float*)d_in[6];
    const float* b0 = (const float*)d_in[7];
    const float* W1 = (const float*)d_in[8];
    const float* b1 = (const float*)d_in[9];
    const float* W2 = (const float*)d_in[10];
    const float* b2 = (const float*)d_in[11];
    int E = in_sizes[0] / 2;
    int N = in_sizes[1] / 8;
    int nbuk = (N + BSZ - 1) >> SHIFT;          // 49 for N=100000

    // workspace layout (bytes), total ~33.7 MB:
    //   qmsg    : nbuk*CAP*8       @ 0
    //   qmeta   : nbuk*CAP*4       @ qmsg_end
    //   partial : nbuk*SEG*BSZ*5*4 @ qmeta_end
    //   tails   : nbuk*64*4        @ partial_end (zeroed)
    char* w = (char*)d_ws;
    size_t qn = (size_t)nbuk * CAP;
    uint2*    qmsg    = (uint2*)w;
    unsigned* qmeta   = (unsigned*)(w + qn * 8);
    unsigned* partial = (unsigned*)(w + qn * 12);
    unsigned* tails   = (unsigned*)(w + qn * 12
                        + (size_t)nbuk * SEG * BSZ * 5 * 4);

    hipMemsetAsync(tails, 0, (size_t)nbuk * 64 * sizeof(unsigned), stream);

    int EB = (E + 1023) / 1024;     // 1563
    route_kernel <<<dim3(EB), dim3(1024), 0, stream>>>(
        ei, f, d, a, w1, w2, tails, qmeta, qmsg, E, nbuk);
    bucket_kernel<<<dim3(nbuk * SEG), dim3(1024), 0, stream>>>(
        tails, qmeta, qmsg, partial, nbuk);
    mlp_kernel   <<<dim3((N + 255) / 256), dim3(256), 0, stream>>>(
        f, partial, W0, b0, W1, b1, W2, b2, (float*)d_out, N);
}